// Round 16
// baseline (158.736 us; speedup 1.0000x reference)
//
#include <hip/hip_runtime.h>
#include <hip/hip_bf16.h>

// ---------------------------------------------------------------------------
// Swin shifted-window attention: fused kernel, TWO windows per block.
//   x:[8,128,128,256] f32, w_qkv:[256,768], pos:[15,15], w_out:[256,256], b_out:[256]
//   out:[8,128,128,256] f32
// One block = window pair (wy, 2wxp)/(wy, 2wxp+1); 512 threads = 8 waves =
// 8 heads. Each weight fragment load feeds MFMAs for BOTH windows (weight
// wave-loads per window 48 -> 24; MFMA slots were 80% idle). 32x32x16 MFMA.
//
// Journal:
//  R1:  fused 8-wave kernel, 64KB LDS                        -> PASS 231 us
//  R2:  bounds(512,6): compiler 40-reg cap                   -> PASS 1873 us (spill)
//  R3:  inline-asm permlane makefrag                         -> FAIL NaN
//  R5:  + Bpack C-init/early-conv/deferred-sum               -> PASS 239 us
//  R7:  sequential Q->K->V                                   -> PASS 225 us
//  R8:  fragment-ordered coalesced packs                     -> PASS 166 us
//  R10: bi-sequential S + merged QK                          -> PASS 163 us
//  R11: bounds(1024,1): 64-reg cap, 1.9GB spill              -> PASS 525 us
//  R14: seq Q,K + unroll 4                                   -> PASS 139 us
//       VGPR 64, occupancy 40.7% (2 blocks/CU), BW 1.3 TB/s. Occupancy
//       model (total V+A <= 128 -> 2 blocks) CONFIRMED.
//  R15: packed cvt in pack2                                  -> PASS 140 us
//       NEUTRAL: VALUBusy unchanged -> compiler already packed. Lever dead.
//       Still latency-bound: 48 L2 weight wave-loads/wave is the backbone
//       (Wpack 512KB/block thrashes 32KB L1; ~250cyc each).
//  R16: 2 windows/block: weight loads amortized 2x, 4 windows in flight at
//       2 blocks/CU. LDS 64KB (x-halves overlaid by O^T after each V pass).
//       Register ledger peak ~120-128 total; unroll 2 caps temps.
//
// MFMA 32x32x16 layouts (verified R1-R15):
//   A-frag: lane l supplies A[m = l%32][k = 8*(l>>5)+i], i=0..7
//   B-frag: lane l supplies B[k = 8*(l>>5)+i][n = l%32]
//   C/D   : (row,col): col = l&31, row = (reg&3) + 8*(reg>>2) + 4*(l>>5)
// ---------------------------------------------------------------------------

typedef __attribute__((ext_vector_type(8)))  short bf16x8;
typedef __attribute__((ext_vector_type(16))) float f32x16;

#define MFMA32(a, b, c) __builtin_amdgcn_mfma_f32_32x32x16_bf16((a), (b), (c), 0, 0, 0)

#define QK_SCALE 0.17677669529663687f  // 1/sqrt(32)
#define LOG2E    1.44269504088896340f

// Packed f32x2 -> bf16x2 (v_cvt_pk_bf16_f32; RNE identical to scalar path).
__device__ __forceinline__ uint32_t pack2(float lo, float hi) {
  float2 f2; f2.x = lo; f2.y = hi;
  __hip_bfloat162 h2 = __float22bfloat162_rn(f2);
  union { __hip_bfloat162 h; uint32_t u; } cv;
  cv.h = h2;
  return cv.u;
}

__device__ __forceinline__ bf16x8 frag_from_u4(uint32_t a, uint32_t b,
                                               uint32_t c, uint32_t d) {
  union { uint32_t u[4]; bf16x8 v; } r;
  r.u[0] = a; r.u[1] = b; r.u[2] = c; r.u[3] = d;
  return r.v;
}

// Fragment re-pack from a 32x32 accumulator: k walks acc ROW index, m/n = col.
// PROVEN shfl_xor form (R1-R15); inline-asm permlane NaN'd in R3.
__device__ __forceinline__ bf16x8 makefrag(const f32x16& a, int kt, int hf) {
  const int b0 = kt * 8;
  uint32_t q0 = pack2(a[b0 + 0], a[b0 + 1]);
  uint32_t q1 = pack2(a[b0 + 2], a[b0 + 3]);
  uint32_t q2 = pack2(a[b0 + 4], a[b0 + 5]);
  uint32_t q3 = pack2(a[b0 + 6], a[b0 + 7]);
  uint32_t x0 = (uint32_t)__shfl_xor((int)q0, 32, 64);
  uint32_t x1 = (uint32_t)__shfl_xor((int)q1, 32, 64);
  uint32_t x2 = (uint32_t)__shfl_xor((int)q2, 32, 64);
  uint32_t x3 = (uint32_t)__shfl_xor((int)q3, 32, 64);
  uint32_t d0 = hf ? x2 : q0;
  uint32_t d1 = hf ? x3 : q1;
  uint32_t d2 = hf ? q2 : x0;
  uint32_t d3 = hf ? q3 : x1;
  return frag_from_u4(d0, d1, d2, d3);
}

// ---------------------------------------------------------------------------
// Prep: FRAGMENT-ORDERED packs (unchanged from R8-R15).
//  Wpack  [sec(3: q,k,v)][h(8)][kt(16)][lane(64)][i(8)] bf16
//  WoPack [h][kt][lane][i] bf16
//  Bpack  [type(4)][ai(2)][bi(2)][rb(4)][lane(64)][j(4)] f32
// ---------------------------------------------------------------------------
__global__ void prep_weights(const float* __restrict__ wqkv,
                             const float* __restrict__ wout,
                             const float* __restrict__ pos,
                             ushort* __restrict__ Wpack,
                             ushort* __restrict__ WoPack,
                             float* __restrict__ Bpack) {
  int id = blockIdx.x * 256 + threadIdx.x;
  if (id < 196608) {                       // 3*8*16*64*8
    int sec = id >> 16;
    int j = id & 65535;
    int h = j >> 13, kt = (j >> 9) & 15, lane = (j >> 3) & 63, i = j & 7;
    int n = h * 32 + (lane & 31);
    int k = kt * 16 + (lane >> 5) * 8 + i;
    float v = wqkv[k * 768 + sec * 256 + n];
    if (sec == 0) v *= QK_SCALE;
    Wpack[id] = __bfloat16_as_ushort(__float2bfloat16(v));
  } else if (id < 262144) {                // + 8*16*64*8
    int j = id - 196608;
    int h = j >> 13, kt = (j >> 9) & 15, lane = (j >> 3) & 63, i = j & 7;
    int n = h * 32 + (lane & 31);
    int k = kt * 16 + (lane >> 5) * 8 + i;
    WoPack[j] = __bfloat16_as_ushort(__float2bfloat16(wout[k * 256 + n]));
  } else if (id < 278528) {                // + 4*2*2*4*64*4
    int j = id - 262144;
    int type = j >> 12;
    int r12 = j & 4095;
    int ai = r12 >> 11, bi = (r12 >> 10) & 1, rb = (r12 >> 8) & 3;
    int lane = (r12 >> 2) & 63, jj = r12 & 3;
    int n = jj + 8 * rb + 4 * (lane >> 5) + 32 * ai;
    int m = (lane & 31) + 32 * bi;
    float v = pos[((n >> 3) - (m >> 3) + 7) * 15 + ((n & 7) - (m & 7) + 7)];
    bool ul = (m >= 32) != (n >= 32);
    bool lr = ((m & 7) >= 4) != ((n & 7) >= 4);
    if (((type & 2) && ul) || ((type & 1) && lr)) v = -1e30f;
    Bpack[j] = v;
  }
}

// ---------------------------------------------------------------------------
__global__ __launch_bounds__(512, 2) void swin_attn(
    const float* __restrict__ x, const float* __restrict__ bout,
    const ushort* __restrict__ Wpack, const ushort* __restrict__ WoPack,
    const float* __restrict__ Bpack, float* __restrict__ out) {
  // 64 KB LDS: window w's x at uint4 offset w*2048 (32 KB each).
  // After V-pass of window w (barriered), its half is overlaid by O^T_w:
  // ushort offset w*16384, slot (kg*64+tok)*8 + 4hf, kg = h*4+g.
  __shared__ uint4 lds[2 * 32 * 64];
  uint4*  ldsX = lds;
  ushort* ldsO = (ushort*)lds;

  const int bid = blockIdx.x;              // 1024 blocks
  const int b   = bid >> 7;
  const int wy  = (bid >> 3) & 15;
  const int wxp = bid & 7;                 // windows wx = 2*wxp, 2*wxp+1
  const int t    = threadIdx.x;
  const int lane = t & 63;
  const int h    = t >> 6;                 // wave id == head id
  const int l31  = lane & 31;
  const int hf   = lane >> 5;

  f32x16 zf;
  #pragma unroll
  for (int i = 0; i < 16; ++i) zf[i] = 0.0f;

  // ---- stage shifted x for BOTH windows -> LDS bf16 ---------------------
  {
    int tok = t >> 3, kc = t & 7;
    int ty = tok >> 3, tx = tok & 7;
    int yy = (wy * 8 + ty + 4) & 127;      // roll(-4,-4) folded into read
    #pragma unroll
    for (int w = 0; w < 2; ++w) {
      int wx = wxp * 2 + w;
      int xx = (wx * 8 + tx + 4) & 127;
      const float* xr = x + (((b * 128 + yy) * 128 + xx) << 8) + kc * 32;
      #pragma unroll
      for (int g = 0; g < 4; ++g) {
        float4 a = *(const float4*)(xr + g * 8);
        float4 c = *(const float4*)(xr + g * 8 + 4);
        uint4 wv;
        wv.x = pack2(a.x, a.y); wv.y = pack2(a.z, a.w);
        wv.z = pack2(c.x, c.y); wv.w = pack2(c.z, c.w);
        int kg = kc * 4 + g;
        ldsX[w * 2048 + ((kg * 64 + tok) ^ kc)] = wv;   // kc == kg>>2
      }
    }
  }
  __syncthreads();

  // Per-head fragment-ordered weight bases (1KB contiguous per wave-load).
  const ushort* wqp = Wpack + h * 8192;            // [kt][lane][8]
  const ushort* wkp = wqp + 65536;
  const ushort* wvp = wkp + 65536;

  // ---- pass Q (both windows share each weight load) ---------------------
  bf16x8 fQ0[2][2], fQ1[2][2];
  {
    f32x16 a00 = zf, a01 = zf, a10 = zf, a11 = zf;   // [win][tok-half]
    #pragma unroll 2
    for (int kt = 0; kt < 16; ++kt) {
      int kg = 2 * kt + hf;
      int s0i = (kg * 64 + l31) ^ (kg >> 2);
      int s1i = (kg * 64 + 32 + l31) ^ (kg >> 2);
      uint4 u00 = ldsX[s0i],        u01 = ldsX[s1i];
      uint4 u10 = ldsX[2048 + s0i], u11 = ldsX[2048 + s1i];
      bf16x8 fw = *(const bf16x8*)(wqp + kt * 512 + lane * 8);
      a00 = MFMA32(fw, frag_from_u4(u00.x, u00.y, u00.z, u00.w), a00);
      a01 = MFMA32(fw, frag_from_u4(u01.x, u01.y, u01.z, u01.w), a01);
      a10 = MFMA32(fw, frag_from_u4(u10.x, u10.y, u10.z, u10.w), a10);
      a11 = MFMA32(fw, frag_from_u4(u11.x, u11.y, u11.z, u11.w), a11);
    }
    #pragma unroll
    for (int kt = 0; kt < 2; ++kt) {
      fQ0[0][kt] = makefrag(a00, kt, hf);
      fQ0[1][kt] = makefrag(a01, kt, hf);
      fQ1[0][kt] = makefrag(a10, kt, hf);
      fQ1[1][kt] = makefrag(a11, kt, hf);
    }
  }

  // ---- pass K (both windows) --------------------------------------------
  bf16x8 fK0[2][2], fK1[2][2];
  {
    f32x16 a00 = zf, a01 = zf, a10 = zf, a11 = zf;
    #pragma unroll 2
    for (int kt = 0; kt < 16; ++kt) {
      int kg = 2 * kt + hf;
      int s0i = (kg * 64 + l31) ^ (kg >> 2);
      int s1i = (kg * 64 + 32 + l31) ^ (kg >> 2);
      uint4 u00 = ldsX[s0i],        u01 = ldsX[s1i];
      uint4 u10 = ldsX[2048 + s0i], u11 = ldsX[2048 + s1i];
      bf16x8 fw = *(const bf16x8*)(wkp + kt * 512 + lane * 8);
      a00 = MFMA32(fw, frag_from_u4(u00.x, u00.y, u00.z, u00.w), a00);
      a01 = MFMA32(fw, frag_from_u4(u01.x, u01.y, u01.z, u01.w), a01);
      a10 = MFMA32(fw, frag_from_u4(u10.x, u10.y, u10.z, u10.w), a10);
      a11 = MFMA32(fw, frag_from_u4(u11.x, u11.y, u11.z, u11.w), a11);
    }
    #pragma unroll
    for (int kt = 0; kt < 2; ++kt) {
      fK0[0][kt] = makefrag(a00, kt, hf);
      fK0[1][kt] = makefrag(a01, kt, hf);
      fK1[0][kt] = makefrag(a10, kt, hf);
      fK1[1][kt] = makefrag(a11, kt, hf);
    }
  }

  // ---- S/softmax/pf per window (bi-sequential, AGPR peak 32) ------------
  bf16x8 pf0[2][4], pf1[2][4];
  float ri0[2], ri1[2];
  const int tybase = (wy == 15) ? 2 : 0;
  #pragma unroll
  for (int w = 0; w < 2; ++w) {
    int wx = wxp * 2 + w;
    const float* Bp = Bpack + ((tybase | ((wx == 15) ? 1 : 0)) << 12);
    #pragma unroll
    for (int bi = 0; bi < 2; ++bi) {
      f32x16 s0, s1;                       // key tiles ai=0,1
      #pragma unroll
      for (int rb = 0; rb < 4; ++rb) {
        float4 f0 = *(const float4*)(Bp + ((bi * 4 + rb) * 64 + lane) * 4);
        float4 f1 = *(const float4*)(Bp + (((2 + bi) * 4 + rb) * 64 + lane) * 4);
        s0[rb * 4 + 0] = f0.x; s0[rb * 4 + 1] = f0.y;
        s0[rb * 4 + 2] = f0.z; s0[rb * 4 + 3] = f0.w;
        s1[rb * 4 + 0] = f1.x; s1[rb * 4 + 1] = f1.y;
        s1[rb * 4 + 2] = f1.z; s1[rb * 4 + 3] = f1.w;
      }
      #pragma unroll
      for (int kt = 0; kt < 2; ++kt) {
        s0 = MFMA32(w ? fK1[0][kt] : fK0[0][kt],
                    w ? fQ1[bi][kt] : fQ0[bi][kt], s0);
        s1 = MFMA32(w ? fK1[1][kt] : fK0[1][kt],
                    w ? fQ1[bi][kt] : fQ0[bi][kt], s1);
      }
      float mx = -3e38f;
      #pragma unroll
      for (int r = 0; r < 16; ++r) mx = fmaxf(mx, fmaxf(s0[r], s1[r]));
      mx = fmaxf(mx, __shfl_xor(mx, 32, 64));
      float sum = 0.0f;
      #pragma unroll
      for (int r = 0; r < 16; ++r) {
        float p0 = exp2f((s0[r] - mx) * LOG2E);
        float p1 = exp2f((s1[r] - mx) * LOG2E);
        s0[r] = p0; s1[r] = p1;
        sum += p0 + p1;
      }
      sum += __shfl_xor(sum, 32, 64);
      float rv = 1.0f / sum;               // deferred to ot scale
      if (w) ri1[bi] = rv; else ri0[bi] = rv;
      #pragma unroll
      for (int kt = 0; kt < 2; ++kt) {
        if (w) {
          pf1[bi][kt]     = makefrag(s0, kt, hf);
          pf1[bi][2 + kt] = makefrag(s1, kt, hf);
        } else {
          pf0[bi][kt]     = makefrag(s0, kt, hf);
          pf0[bi][2 + kt] = makefrag(s1, kt, hf);
        }
      }
    }
  }

  // ---- per window: V pass -> (barrier) -> PV -> spill O^T ---------------
  #pragma unroll
  for (int w = 0; w < 2; ++w) {
    bf16x8 fV[2][2];
    {
      f32x16 a0 = zf, a1 = zf;
      #pragma unroll 2
      for (int kt = 0; kt < 16; ++kt) {
        int kg = 2 * kt + hf;
        int s0i = (kg * 64 + l31) ^ (kg >> 2);
        int s1i = (kg * 64 + 32 + l31) ^ (kg >> 2);
        uint4 ux0 = ldsX[w * 2048 + s0i];
        uint4 ux1 = ldsX[w * 2048 + s1i];
        bf16x8 fw = *(const bf16x8*)(wvp + kt * 512 + lane * 8);
        a0 = MFMA32(frag_from_u4(ux0.x, ux0.y, ux0.z, ux0.w), fw, a0);
        a1 = MFMA32(frag_from_u4(ux1.x, ux1.y, ux1.z, ux1.w), fw, a1);
      }
      #pragma unroll
      for (int kt = 0; kt < 2; ++kt) {
        fV[0][kt] = makefrag(a0, kt, hf);
        fV[1][kt] = makefrag(a1, kt, hf);
      }
    }
    // all waves done reading x_w before O^T_w overlays its region
    __syncthreads();

    f32x16 ot[2];
    ot[0] = zf; ot[1] = zf;
    #pragma unroll
    for (int jt = 0; jt < 4; ++jt) {
      bf16x8 aV = fV[jt >> 1][jt & 1];
      ot[0] = MFMA32(aV, w ? pf1[0][jt] : pf0[0][jt], ot[0]);
      ot[1] = MFMA32(aV, w ? pf1[1][jt] : pf0[1][jt], ot[1]);
    }
    #pragma unroll
    for (int bi = 0; bi < 2; ++bi) {
      float rv = w ? ri1[bi] : ri0[bi];
      #pragma unroll
      for (int r = 0; r < 16; ++r) ot[bi][r] *= rv;
    }

    // O^T_w -> LDS (k = h*32 + d slots over 64 tokens; 32 KB region w)
    #pragma unroll
    for (int bi = 0; bi < 2; ++bi) {
      int tok = bi * 32 + l31;
      #pragma unroll
      for (int g = 0; g < 4; ++g) {
        int kg = h * 4 + g;                // d = 8g + 4hf + 0..3
        uint2 wv2;
        wv2.x = pack2(ot[bi][4 * g + 0], ot[bi][4 * g + 1]);
        wv2.y = pack2(ot[bi][4 * g + 2], ot[bi][4 * g + 3]);
        *(uint2*)&ldsO[w * 16384 + (kg * 64 + tok) * 8 + 4 * hf] = wv2;
      }
    }
  }
  __syncthreads();                         // all O^T spills visible

  // ---- out-proj both windows (shared wop load): wave h -> cols h*32..+31
  const ushort* wop = WoPack + h * 8192;
  f32x16 u00 = zf, u01 = zf, u10 = zf, u11 = zf;
  #pragma unroll 2
  for (int kt = 0; kt < 16; ++kt) {
    int kg = 2 * kt + hf;
    bf16x8 wa = *(const bf16x8*)(wop + kt * 512 + lane * 8);
    bf16x8 b00 = *(const bf16x8*)&ldsO[(kg * 64 + l31) * 8];
    bf16x8 b01 = *(const bf16x8*)&ldsO[(kg * 64 + 32 + l31) * 8];
    bf16x8 b10 = *(const bf16x8*)&ldsO[16384 + (kg * 64 + l31) * 8];
    bf16x8 b11 = *(const bf16x8*)&ldsO[16384 + (kg * 64 + 32 + l31) * 8];
    u00 = MFMA32(wa, b00, u00);  u01 = MFMA32(wa, b01, u01);
    u10 = MFMA32(wa, b10, u10);  u11 = MFMA32(wa, b11, u11);
  }

  // ---- epilogue: + b_out, write fp32 with roll(+4,+4) folded in ---------
  #pragma unroll
  for (int w = 0; w < 2; ++w) {
    int wx = wxp * 2 + w;
    #pragma unroll
    for (int tt = 0; tt < 2; ++tt) {
      const f32x16& u = w ? (tt ? u11 : u10) : (tt ? u01 : u00);
      int tok = 32 * tt + l31;
      int ty = tok >> 3, tx = tok & 7;
      int yy = (wy * 8 + ty + 4) & 127;
      int xx = (wx * 8 + tx + 4) & 127;
      float* ob = out + (((b * 128 + yy) * 128 + xx) << 8);
      #pragma unroll
      for (int g = 0; g < 4; ++g) {
        int c0 = h * 32 + 8 * g + 4 * hf;
        float4 bo = *(const float4*)(bout + c0);
        float4 v;
        v.x = u[4 * g + 0] + bo.x;
        v.y = u[4 * g + 1] + bo.y;
        v.z = u[4 * g + 2] + bo.z;
        v.w = u[4 * g + 3] + bo.w;
        *(float4*)(ob + c0) = v;
      }
    }
  }
}

// ---------------------------------------------------------------------------
extern "C" void kernel_launch(void* const* d_in, const int* in_sizes, int n_in,
                              void* d_out, int out_size, void* d_ws, size_t ws_size,
                              hipStream_t stream) {
  const float* x    = (const float*)d_in[0];
  const float* wqkv = (const float*)d_in[1];
  const float* pos  = (const float*)d_in[2];
  const float* wout = (const float*)d_in[3];
  const float* bout = (const float*)d_in[4];

  ushort* Wpack  = (ushort*)d_ws;                     // [3][8][16][64][8] bf16
  ushort* WoPack = Wpack + 196608;                    // [8][16][64][8] bf16
  float*  Bpack  = (float*)((char*)d_ws + 524288);    // [4][2][2][4][64][4] f32

  prep_weights<<<1088, 256, 0, stream>>>(wqkv, wout, pos, Wpack, WoPack, Bpack);
  swin_attn<<<1024, 512, 0, stream>>>(x, bout, Wpack, WoPack, Bpack, (float*)d_out);
}

// Round 17
// 141.992 us; speedup vs baseline: 1.1179x; 1.1179x over previous
//
#include <hip/hip_runtime.h>
#include <hip/hip_bf16.h>

// ---------------------------------------------------------------------------
// Swin shifted-window attention, fully fused per-window kernel.
//   x:[8,128,128,256] f32, w_qkv:[256,768], pos:[15,15], w_out:[256,256], b_out:[256]
//   out:[8,128,128,256] f32
// One block = one window; 512 threads = 8 waves = 8 heads. 32x32x16 bf16 MFMA.
//
// Journal:
//  R1:  fused 8-wave kernel                                  -> PASS 231 us
//  R2:  bounds(512,6): compiler 40-reg cap                   -> PASS 1873 us (spill)
//  R3:  inline-asm permlane makefrag                         -> FAIL NaN
//  R5:  + Bpack C-init/early-conv/deferred-sum               -> PASS 239 us
//  R7:  sequential Q->K->V                                   -> PASS 225 us
//  R8:  fragment-ordered coalesced packs                     -> PASS 166 us
//  R10: bi-sequential S + merged QK                          -> PASS 163 us
//  R11: bounds(1024,1): 64-reg cap, 1.9GB spill              -> PASS 525 us
//  R14: seq Q,K (32A peaks) + unroll 4                       -> PASS 139 us
//       VGPR 64, occupancy 40.7% (2 blocks/CU). Occupancy model (total
//       V+A <= 128 -> 2 blocks) CONFIRMED.
//  R15: packed cvt in pack2                                  -> PASS 140 us (neutral)
//  R16: 2 windows/block (64KB LDS, 4-acc phases)             -> PASS 159 us
//       REGRESSED: 64A phases -> total >128 -> occupancy back to 21%.
//       Cliff lesson: shared-load schemes double acc state -> off the cliff.
//  R17: revert to R14/R15; unroll 4 -> 8 on Q/K/V kt-loops only (2x
//       in-flight L2 weight loads + LDS reads; ledger V~96 total~128).
//
// MFMA 32x32x16 layouts (verified R1-R16):
//   A-frag: lane l supplies A[m = l%32][k = 8*(l>>5)+i], i=0..7
//   B-frag: lane l supplies B[k = 8*(l>>5)+i][n = l%32]
//   C/D   : (row,col): col = l&31, row = (reg&3) + 8*(reg>>2) + 4*(l>>5)
// ---------------------------------------------------------------------------

typedef __attribute__((ext_vector_type(8)))  short bf16x8;
typedef __attribute__((ext_vector_type(16))) float f32x16;

#define MFMA32(a, b, c) __builtin_amdgcn_mfma_f32_32x32x16_bf16((a), (b), (c), 0, 0, 0)

#define QK_SCALE 0.17677669529663687f  // 1/sqrt(32)
#define LOG2E    1.44269504088896340f

// Packed f32x2 -> bf16x2 (v_cvt_pk_bf16_f32; RNE identical to scalar path).
__device__ __forceinline__ uint32_t pack2(float lo, float hi) {
  float2 f2; f2.x = lo; f2.y = hi;
  __hip_bfloat162 h2 = __float22bfloat162_rn(f2);
  union { __hip_bfloat162 h; uint32_t u; } cv;
  cv.h = h2;
  return cv.u;
}

__device__ __forceinline__ bf16x8 frag_from_u4(uint32_t a, uint32_t b,
                                               uint32_t c, uint32_t d) {
  union { uint32_t u[4]; bf16x8 v; } r;
  r.u[0] = a; r.u[1] = b; r.u[2] = c; r.u[3] = d;
  return r.v;
}

// Fragment re-pack from a 32x32 accumulator: k walks acc ROW index, m/n = col.
// PROVEN shfl_xor form (R1-R16); inline-asm permlane NaN'd in R3.
__device__ __forceinline__ bf16x8 makefrag(const f32x16& a, int kt, int hf) {
  const int b0 = kt * 8;
  uint32_t q0 = pack2(a[b0 + 0], a[b0 + 1]);
  uint32_t q1 = pack2(a[b0 + 2], a[b0 + 3]);
  uint32_t q2 = pack2(a[b0 + 4], a[b0 + 5]);
  uint32_t q3 = pack2(a[b0 + 6], a[b0 + 7]);
  uint32_t x0 = (uint32_t)__shfl_xor((int)q0, 32, 64);
  uint32_t x1 = (uint32_t)__shfl_xor((int)q1, 32, 64);
  uint32_t x2 = (uint32_t)__shfl_xor((int)q2, 32, 64);
  uint32_t x3 = (uint32_t)__shfl_xor((int)q3, 32, 64);
  uint32_t d0 = hf ? x2 : q0;
  uint32_t d1 = hf ? x3 : q1;
  uint32_t d2 = hf ? q2 : x0;
  uint32_t d3 = hf ? q3 : x1;
  return frag_from_u4(d0, d1, d2, d3);
}

// ---------------------------------------------------------------------------
// Prep: FRAGMENT-ORDERED packs (unchanged from R8-R16).
//  Wpack  [sec(3: q,k,v)][h(8)][kt(16)][lane(64)][i(8)] bf16
//  WoPack [h][kt][lane][i] bf16
//  Bpack  [type(4)][ai(2)][bi(2)][rb(4)][lane(64)][j(4)] f32
// ---------------------------------------------------------------------------
__global__ void prep_weights(const float* __restrict__ wqkv,
                             const float* __restrict__ wout,
                             const float* __restrict__ pos,
                             ushort* __restrict__ Wpack,
                             ushort* __restrict__ WoPack,
                             float* __restrict__ Bpack) {
  int id = blockIdx.x * 256 + threadIdx.x;
  if (id < 196608) {                       // 3*8*16*64*8
    int sec = id >> 16;
    int j = id & 65535;
    int h = j >> 13, kt = (j >> 9) & 15, lane = (j >> 3) & 63, i = j & 7;
    int n = h * 32 + (lane & 31);
    int k = kt * 16 + (lane >> 5) * 8 + i;
    float v = wqkv[k * 768 + sec * 256 + n];
    if (sec == 0) v *= QK_SCALE;
    Wpack[id] = __bfloat16_as_ushort(__float2bfloat16(v));
  } else if (id < 262144) {                // + 8*16*64*8
    int j = id - 196608;
    int h = j >> 13, kt = (j >> 9) & 15, lane = (j >> 3) & 63, i = j & 7;
    int n = h * 32 + (lane & 31);
    int k = kt * 16 + (lane >> 5) * 8 + i;
    WoPack[j] = __bfloat16_as_ushort(__float2bfloat16(wout[k * 256 + n]));
  } else if (id < 278528) {                // + 4*2*2*4*64*4
    int j = id - 262144;
    int type = j >> 12;
    int r12 = j & 4095;
    int ai = r12 >> 11, bi = (r12 >> 10) & 1, rb = (r12 >> 8) & 3;
    int lane = (r12 >> 2) & 63, jj = r12 & 3;
    int n = jj + 8 * rb + 4 * (lane >> 5) + 32 * ai;
    int m = (lane & 31) + 32 * bi;
    float v = pos[((n >> 3) - (m >> 3) + 7) * 15 + ((n & 7) - (m & 7) + 7)];
    bool ul = (m >= 32) != (n >= 32);
    bool lr = ((m & 7) >= 4) != ((n & 7) >= 4);
    if (((type & 2) && ul) || ((type & 1) && lr)) v = -1e30f;
    Bpack[j] = v;
  }
}

// ---------------------------------------------------------------------------
__global__ __launch_bounds__(512, 2) void swin_attn(
    const float* __restrict__ x, const float* __restrict__ bout,
    const ushort* __restrict__ Wpack, const ushort* __restrict__ WoPack,
    const float* __restrict__ Bpack, float* __restrict__ out) {
  // 32 KB union: phases 0-2 x-window bf16 (k-grouped, swizzled);
  // phases 3-4 O^T bf16 (same k-grouped slot layout, k = h*32+d).
  __shared__ uint4 lds[32 * 64];
  uint4*  ldsX = lds;
  ushort* ldsO = (ushort*)lds;

  const int bid = blockIdx.x;
  const int b  = bid >> 8;
  const int wy = (bid >> 4) & 15;
  const int wx = bid & 15;
  const int t    = threadIdx.x;
  const int lane = t & 63;
  const int h    = t >> 6;                 // wave id == head id
  const int l31  = lane & 31;
  const int hf   = lane >> 5;

  f32x16 zf;
  #pragma unroll
  for (int i = 0; i < 16; ++i) zf[i] = 0.0f;

  // ---- stage shifted x window -> LDS bf16 -------------------------------
  {
    int tok = t >> 3, kc = t & 7;
    int ty = tok >> 3, tx = tok & 7;
    int yy = (wy * 8 + ty + 4) & 127;      // roll(-4,-4) folded into read
    int xx = (wx * 8 + tx + 4) & 127;
    const float* xr = x + (((b * 128 + yy) * 128 + xx) << 8) + kc * 32;
    #pragma unroll
    for (int g = 0; g < 4; ++g) {
      float4 a = *(const float4*)(xr + g * 8);
      float4 c = *(const float4*)(xr + g * 8 + 4);
      uint4 w;
      w.x = pack2(a.x, a.y); w.y = pack2(a.z, a.w);
      w.z = pack2(c.x, c.y); w.w = pack2(c.z, c.w);
      int kg = kc * 4 + g;
      ldsX[(kg * 64 + tok) ^ kc] = w;      // kc == kg>>2
    }
  }
  __syncthreads();

  // Per-head fragment-ordered weight bases (1KB contiguous per wave-load).
  const ushort* wqp = Wpack + h * 8192;            // [kt][lane][8]
  const ushort* wkp = wqp + 65536;
  const ushort* wvp = wkp + 65536;

  // ---- pass Q: Q^T = Wq · X^T  (unroll 8: 2x in-flight loads) -----------
  bf16x8 fQ[2][2];
  {
    f32x16 a0 = zf, a1 = zf;
    #pragma unroll 8
    for (int kt = 0; kt < 16; ++kt) {
      int kg = 2 * kt + hf;
      uint4 ux0 = ldsX[(kg * 64 + l31) ^ (kg >> 2)];
      uint4 ux1 = ldsX[(kg * 64 + 32 + l31) ^ (kg >> 2)];
      bf16x8 xf0 = frag_from_u4(ux0.x, ux0.y, ux0.z, ux0.w);
      bf16x8 xf1 = frag_from_u4(ux1.x, ux1.y, ux1.z, ux1.w);
      bf16x8 fw = *(const bf16x8*)(wqp + kt * 512 + lane * 8);
      a0 = MFMA32(fw, xf0, a0);  a1 = MFMA32(fw, xf1, a1);
    }
    #pragma unroll
    for (int kt = 0; kt < 2; ++kt) {
      fQ[0][kt] = makefrag(a0, kt, hf);
      fQ[1][kt] = makefrag(a1, kt, hf);
    }
  }

  // ---- pass K: K^T = Wk · X^T -------------------------------------------
  bf16x8 fK[2][2];
  {
    f32x16 a0 = zf, a1 = zf;
    #pragma unroll 8
    for (int kt = 0; kt < 16; ++kt) {
      int kg = 2 * kt + hf;
      uint4 ux0 = ldsX[(kg * 64 + l31) ^ (kg >> 2)];
      uint4 ux1 = ldsX[(kg * 64 + 32 + l31) ^ (kg >> 2)];
      bf16x8 xf0 = frag_from_u4(ux0.x, ux0.y, ux0.z, ux0.w);
      bf16x8 xf1 = frag_from_u4(ux1.x, ux1.y, ux1.z, ux1.w);
      bf16x8 fw = *(const bf16x8*)(wkp + kt * 512 + lane * 8);
      a0 = MFMA32(fw, xf0, a0);  a1 = MFMA32(fw, xf1, a1);
    }
    #pragma unroll
    for (int kt = 0; kt < 2; ++kt) {
      fK[0][kt] = makefrag(a0, kt, hf);
      fK[1][kt] = makefrag(a1, kt, hf);
    }
  }

  // ---- bi-sequential S/softmax/P-conversion (AGPR peak 32) --------------
  const float* Bp = Bpack + ((((wy == 15) ? 2 : 0) | ((wx == 15) ? 1 : 0)) << 12);
  bf16x8 pf[2][4];
  float ri[2];
  #pragma unroll
  for (int bi = 0; bi < 2; ++bi) {
    f32x16 s0, s1;                         // S^T key-tiles ai=0,1 for this bi
    #pragma unroll
    for (int rb = 0; rb < 4; ++rb) {
      float4 f0 = *(const float4*)(Bp + ((bi * 4 + rb) * 64 + lane) * 4);
      float4 f1 = *(const float4*)(Bp + (((2 + bi) * 4 + rb) * 64 + lane) * 4);
      s0[rb * 4 + 0] = f0.x; s0[rb * 4 + 1] = f0.y;
      s0[rb * 4 + 2] = f0.z; s0[rb * 4 + 3] = f0.w;
      s1[rb * 4 + 0] = f1.x; s1[rb * 4 + 1] = f1.y;
      s1[rb * 4 + 2] = f1.z; s1[rb * 4 + 3] = f1.w;
    }
    #pragma unroll
    for (int kt = 0; kt < 2; ++kt) {
      s0 = MFMA32(fK[0][kt], fQ[bi][kt], s0);
      s1 = MFMA32(fK[1][kt], fQ[bi][kt], s1);
    }
    float mx = -3e38f;
    #pragma unroll
    for (int r = 0; r < 16; ++r) mx = fmaxf(mx, fmaxf(s0[r], s1[r]));
    mx = fmaxf(mx, __shfl_xor(mx, 32, 64));
    float sum = 0.0f;
    #pragma unroll
    for (int r = 0; r < 16; ++r) {
      float p0 = exp2f((s0[r] - mx) * LOG2E);
      float p1 = exp2f((s1[r] - mx) * LOG2E);
      s0[r] = p0; s1[r] = p1;
      sum += p0 + p1;
    }
    sum += __shfl_xor(sum, 32, 64);
    ri[bi] = 1.0f / sum;                   // deferred to ot scale
    #pragma unroll
    for (int kt = 0; kt < 2; ++kt) {
      pf[bi][kt]     = makefrag(s0, kt, hf);
      pf[bi][2 + kt] = makefrag(s1, kt, hf);
    }
  }

  // ---- pass V: V = X · Wv (fQ/fK dead) ----------------------------------
  bf16x8 fV[2][2];
  {
    f32x16 a0 = zf, a1 = zf;
    #pragma unroll 8
    for (int kt = 0; kt < 16; ++kt) {
      int kg = 2 * kt + hf;
      uint4 ux0 = ldsX[(kg * 64 + l31) ^ (kg >> 2)];
      uint4 ux1 = ldsX[(kg * 64 + 32 + l31) ^ (kg >> 2)];
      bf16x8 xf0 = frag_from_u4(ux0.x, ux0.y, ux0.z, ux0.w);
      bf16x8 xf1 = frag_from_u4(ux1.x, ux1.y, ux1.z, ux1.w);
      bf16x8 fw = *(const bf16x8*)(wvp + kt * 512 + lane * 8);
      a0 = MFMA32(xf0, fw, a0);  a1 = MFMA32(xf1, fw, a1);
    }
    #pragma unroll
    for (int kt = 0; kt < 2; ++kt) {
      fV[0][kt] = makefrag(a0, kt, hf);
      fV[1][kt] = makefrag(a1, kt, hf);
    }
  }

  // ---- O^T = V^T · P^T  (ot[bi]: row=d, col=query token) ----------------
  f32x16 ot[2];
  ot[0] = zf; ot[1] = zf;
  #pragma unroll
  for (int jt = 0; jt < 4; ++jt) {
    bf16x8 aV = fV[jt >> 1][jt & 1];
    ot[0] = MFMA32(aV, pf[0][jt], ot[0]);
    ot[1] = MFMA32(aV, pf[1][jt], ot[1]);
  }
  #pragma unroll
  for (int bi = 0; bi < 2; ++bi)
    #pragma unroll
    for (int r = 0; r < 16; ++r) ot[bi][r] *= ri[bi];

  // all waves must be done reading ldsX before ldsO overwrites the union
  __syncthreads();

  // ---- O^T -> LDS bf16 (k = h*32 + d, k-grouped slots) ------------------
  {
    #pragma unroll
    for (int bi = 0; bi < 2; ++bi) {
      int tok = bi * 32 + l31;
      #pragma unroll
      for (int g = 0; g < 4; ++g) {
        int kg = h * 4 + g;                // d = 8g + 4hf + 0..3
        uint2 wv2;
        wv2.x = pack2(ot[bi][4 * g + 0], ot[bi][4 * g + 1]);
        wv2.y = pack2(ot[bi][4 * g + 2], ot[bi][4 * g + 3]);
        *(uint2*)&ldsO[(kg * 64 + tok) * 8 + 4 * hf] = wv2;
      }
    }
  }
  __syncthreads();

  // ---- out-proj: out^T = W_out^T · O^T  (wave h -> out cols h*32..+31) --
  const ushort* wop = WoPack + h * 8192;
  f32x16 u[2];
  u[0] = zf; u[1] = zf;
  #pragma unroll 4
  for (int kt = 0; kt < 16; ++kt) {
    int kg = 2 * kt + hf;
    bf16x8 wa = *(const bf16x8*)(wop + kt * 512 + lane * 8);
    bf16x8 b0 = *(const bf16x8*)&ldsO[(kg * 64 + l31) * 8];
    bf16x8 b1 = *(const bf16x8*)&ldsO[(kg * 64 + 32 + l31) * 8];
    u[0] = MFMA32(wa, b0, u[0]);
    u[1] = MFMA32(wa, b1, u[1]);
  }

  // ---- epilogue: + b_out, write fp32 with roll(+4,+4) folded in ---------
  #pragma unroll
  for (int tt = 0; tt < 2; ++tt) {
    int tok = 32 * tt + l31;
    int ty = tok >> 3, tx = tok & 7;
    int yy = (wy * 8 + ty + 4) & 127;
    int xx = (wx * 8 + tx + 4) & 127;
    float* ob = out + (((b * 128 + yy) * 128 + xx) << 8);
    #pragma unroll
    for (int g = 0; g < 4; ++g) {
      int c0 = h * 32 + 8 * g + 4 * hf;
      float4 bo = *(const float4*)(bout + c0);
      float4 v;
      v.x = (tt ? u[1][4 * g + 0] : u[0][4 * g + 0]) + bo.x;
      v.y = (tt ? u[1][4 * g + 1] : u[0][4 * g + 1]) + bo.y;
      v.z = (tt ? u[1][4 * g + 2] : u[0][4 * g + 2]) + bo.z;
      v.w = (tt ? u[1][4 * g + 3] : u[0][4 * g + 3]) + bo.w;
      *(float4*)(ob + c0) = v;
    }
  }
}

// ---------------------------------------------------------------------------
extern "C" void kernel_launch(void* const* d_in, const int* in_sizes, int n_in,
                              void* d_out, int out_size, void* d_ws, size_t ws_size,
                              hipStream_t stream) {
  const float* x    = (const float*)d_in[0];
  const float* wqkv = (const float*)d_in[1];
  const float* pos  = (const float*)d_in[2];
  const float* wout = (const float*)d_in[3];
  const float* bout = (const float*)d_in[4];

  ushort* Wpack  = (ushort*)d_ws;                     // [3][8][16][64][8] bf16
  ushort* WoPack = Wpack + 196608;                    // [8][16][64][8] bf16
  float*  Bpack  = (float*)((char*)d_ws + 524288);    // [4][2][2][4][64][4] f32

  prep_weights<<<1088, 256, 0, stream>>>(wqkv, wout, pos, Wpack, WoPack, Bpack);
  swin_attn<<<2048, 512, 0, stream>>>(x, bout, Wpack, WoPack, Bpack, (float*)d_out);
}

// Round 18
// 133.646 us; speedup vs baseline: 1.1877x; 1.0624x over previous
//
#include <hip/hip_runtime.h>
#include <hip/hip_bf16.h>

// ---------------------------------------------------------------------------
// Swin shifted-window attention, fully fused per-window kernel.
//   x:[8,128,128,256] f32, w_qkv:[256,768], pos:[15,15], w_out:[256,256], b_out:[256]
//   out:[8,128,128,256] f32
// One block = one window; 512 threads = 8 waves = 8 heads. 32x32x16 bf16 MFMA.
//
// Journal:
//  R1:  fused 8-wave kernel                                  -> PASS 231 us
//  R2:  bounds(512,6): compiler 40-reg cap                   -> PASS 1873 us (spill)
//  R3:  RAW INLINE-ASM permlane makefrag                     -> FAIL NaN
//       (no hazard modeling around opaque asm; builtin form is safe)
//  R5:  + Bpack C-init/early-conv/deferred-sum               -> PASS 239 us
//  R7:  sequential Q->K->V                                   -> PASS 225 us
//  R8:  fragment-ordered coalesced packs                     -> PASS 166 us
//  R10: bi-sequential S + merged QK                          -> PASS 163 us
//  R14: seq Q,K (32A peaks) + unroll 4                       -> PASS 139 us  *BEST*
//       VGPR 64, occupancy 40.7% (2 blocks/CU). Total V+A <= 128 model OK.
//  R15: packed cvt in pack2                                  -> PASS 140 us (neutral)
//  R16: 2 windows/block                                      -> PASS 159 us (occ cliff)
//  R17: unroll 8                                             -> PASS 142 us (neutral;
//       compiler ignores deeper unroll for scheduling)
//  R18: makefrag via __builtin_amdgcn_permlane32_swap (T12 builtin, hazard-
//       safe unlike R3's asm): 1 VALU permlane yields BOTH d0,d2 -> drops
//       56 ds_bpermute (LDS-pipe waits) + 56 cndmask per wave. Plus
//       provably-identical LDS addr decomposition:
//       (kg*64+l31)^(kg>>2) == kg*64 + (l31^(kt>>1))  [XOR<=7 only hits l31
//       bits; (2kt+hf)>>2 == kt>>1 for hf in {0,1}] -> CSE + imm folding.
//       Wv*Wo-fold restructure costed and ABANDONED (VALU-issue would grow
//       past current total; reg/LDS cliffs).
//
// MFMA 32x32x16 layouts (verified R1-R17):
//   A-frag: lane l supplies A[m = l%32][k = 8*(l>>5)+i], i=0..7
//   B-frag: lane l supplies B[k = 8*(l>>5)+i][n = l%32]
//   C/D   : (row,col): col = l&31, row = (reg&3) + 8*(reg>>2) + 4*(l>>5)
// ---------------------------------------------------------------------------

typedef __attribute__((ext_vector_type(8)))  short bf16x8;
typedef __attribute__((ext_vector_type(16))) float f32x16;
typedef __attribute__((ext_vector_type(2)))  unsigned int u32x2;

#define MFMA32(a, b, c) __builtin_amdgcn_mfma_f32_32x32x16_bf16((a), (b), (c), 0, 0, 0)

#define QK_SCALE 0.17677669529663687f  // 1/sqrt(32)
#define LOG2E    1.44269504088896340f

// Packed f32x2 -> bf16x2 (v_cvt_pk_bf16_f32; RNE identical to scalar path).
__device__ __forceinline__ uint32_t pack2(float lo, float hi) {
  float2 f2; f2.x = lo; f2.y = hi;
  __hip_bfloat162 h2 = __float22bfloat162_rn(f2);
  union { __hip_bfloat162 h; uint32_t u; } cv;
  cv.h = h2;
  return cv.u;
}

__device__ __forceinline__ bf16x8 frag_from_u4(uint32_t a, uint32_t b,
                                               uint32_t c, uint32_t d) {
  union { uint32_t u[4]; bf16x8 v; } r;
  r.u[0] = a; r.u[1] = b; r.u[2] = c; r.u[3] = d;
  return r.v;
}

// Fragment re-pack from a 32x32 accumulator: k walks acc ROW index, m/n = col.
// v_permlane32_swap_b32(q0,q2) swaps q0's upper 32 lanes with q2's lower 32:
//   result.x = [q0(0..31), q2(0..31)]  == old d0 (hf? x2 : q0)
//   result.y = [q0(32..63), q2(32..63)] == old d2 (hf? q2 : x0)
// One instruction produces both fragment words; compiler handles hazards
// (R3's raw-asm version lacked that and NaN'd).
__device__ __forceinline__ bf16x8 makefrag(const f32x16& a, int kt, int hf) {
  const int b0 = kt * 8;
  uint32_t q0 = pack2(a[b0 + 0], a[b0 + 1]);
  uint32_t q1 = pack2(a[b0 + 2], a[b0 + 3]);
  uint32_t q2 = pack2(a[b0 + 4], a[b0 + 5]);
  uint32_t q3 = pack2(a[b0 + 6], a[b0 + 7]);
  u32x2 r02 = __builtin_amdgcn_permlane32_swap(q0, q2, false, false);
  u32x2 r13 = __builtin_amdgcn_permlane32_swap(q1, q3, false, false);
  return frag_from_u4(r02.x, r13.x, r02.y, r13.y);
}

// ---------------------------------------------------------------------------
// Prep: FRAGMENT-ORDERED packs (unchanged from R8-R17).
//  Wpack  [sec(3: q,k,v)][h(8)][kt(16)][lane(64)][i(8)] bf16
//  WoPack [h][kt][lane][i] bf16
//  Bpack  [type(4)][ai(2)][bi(2)][rb(4)][lane(64)][j(4)] f32
// ---------------------------------------------------------------------------
__global__ void prep_weights(const float* __restrict__ wqkv,
                             const float* __restrict__ wout,
                             const float* __restrict__ pos,
                             ushort* __restrict__ Wpack,
                             ushort* __restrict__ WoPack,
                             float* __restrict__ Bpack) {
  int id = blockIdx.x * 256 + threadIdx.x;
  if (id < 196608) {                       // 3*8*16*64*8
    int sec = id >> 16;
    int j = id & 65535;
    int h = j >> 13, kt = (j >> 9) & 15, lane = (j >> 3) & 63, i = j & 7;
    int n = h * 32 + (lane & 31);
    int k = kt * 16 + (lane >> 5) * 8 + i;
    float v = wqkv[k * 768 + sec * 256 + n];
    if (sec == 0) v *= QK_SCALE;
    Wpack[id] = __bfloat16_as_ushort(__float2bfloat16(v));
  } else if (id < 262144) {                // + 8*16*64*8
    int j = id - 196608;
    int h = j >> 13, kt = (j >> 9) & 15, lane = (j >> 3) & 63, i = j & 7;
    int n = h * 32 + (lane & 31);
    int k = kt * 16 + (lane >> 5) * 8 + i;
    WoPack[j] = __bfloat16_as_ushort(__float2bfloat16(wout[k * 256 + n]));
  } else if (id < 278528) {                // + 4*2*2*4*64*4
    int j = id - 262144;
    int type = j >> 12;
    int r12 = j & 4095;
    int ai = r12 >> 11, bi = (r12 >> 10) & 1, rb = (r12 >> 8) & 3;
    int lane = (r12 >> 2) & 63, jj = r12 & 3;
    int n = jj + 8 * rb + 4 * (lane >> 5) + 32 * ai;
    int m = (lane & 31) + 32 * bi;
    float v = pos[((n >> 3) - (m >> 3) + 7) * 15 + ((n & 7) - (m & 7) + 7)];
    bool ul = (m >= 32) != (n >= 32);
    bool lr = ((m & 7) >= 4) != ((n & 7) >= 4);
    if (((type & 2) && ul) || ((type & 1) && lr)) v = -1e30f;
    Bpack[j] = v;
  }
}

// ---------------------------------------------------------------------------
__global__ __launch_bounds__(512, 2) void swin_attn(
    const float* __restrict__ x, const float* __restrict__ bout,
    const ushort* __restrict__ Wpack, const ushort* __restrict__ WoPack,
    const float* __restrict__ Bpack, float* __restrict__ out) {
  // 32 KB union: phases 0-2 x-window bf16 (k-grouped, swizzled);
  // phases 3-4 O^T bf16 (same k-grouped slot layout, k = h*32+d).
  __shared__ uint4 lds[32 * 64];
  uint4*  ldsX = lds;
  ushort* ldsO = (ushort*)lds;

  const int bid = blockIdx.x;
  const int b  = bid >> 8;
  const int wy = (bid >> 4) & 15;
  const int wx = bid & 15;
  const int t    = threadIdx.x;
  const int lane = t & 63;
  const int h    = t >> 6;                 // wave id == head id
  const int l31  = lane & 31;
  const int hf   = lane >> 5;

  f32x16 zf;
  #pragma unroll
  for (int i = 0; i < 16; ++i) zf[i] = 0.0f;

  // ---- stage shifted x window -> LDS bf16 -------------------------------
  {
    int tok = t >> 3, kc = t & 7;
    int ty = tok >> 3, tx = tok & 7;
    int yy = (wy * 8 + ty + 4) & 127;      // roll(-4,-4) folded into read
    int xx = (wx * 8 + tx + 4) & 127;
    const float* xr = x + (((b * 128 + yy) * 128 + xx) << 8) + kc * 32;
    #pragma unroll
    for (int g = 0; g < 4; ++g) {
      float4 a = *(const float4*)(xr + g * 8);
      float4 c = *(const float4*)(xr + g * 8 + 4);
      uint4 w;
      w.x = pack2(a.x, a.y); w.y = pack2(a.z, a.w);
      w.z = pack2(c.x, c.y); w.w = pack2(c.z, c.w);
      int kg = kc * 4 + g;
      ldsX[(kg * 64 + tok) ^ kc] = w;      // kc == kg>>2
    }
  }
  __syncthreads();

  // Per-head fragment-ordered weight bases (1KB contiguous per wave-load).
  const ushort* wqp = Wpack + h * 8192;            // [kt][lane][8]
  const ushort* wkp = wqp + 65536;
  const ushort* wvp = wkp + 65536;

  // Decomposed LDS read addressing: idx = (2kt+hf)*64 + (l31 ^ (kt>>1)).
  // Equal to ((2kt+hf)*64 + l31) ^ ((2kt+hf)>>2): XOR operand <= 7 touches
  // only l31's bits, and (2kt+hf)>>2 == kt>>1 for hf in {0,1}.

  // ---- pass Q: Q^T = Wq · X^T  (unroll 4) -------------------------------
  bf16x8 fQ[2][2];
  {
    f32x16 a0 = zf, a1 = zf;
    #pragma unroll 4
    for (int kt = 0; kt < 16; ++kt) {
      int lx = l31 ^ (kt >> 1);
      int base = (2 * kt + hf) * 64;
      uint4 ux0 = ldsX[base + lx];
      uint4 ux1 = ldsX[base + 32 + ((l31 + 32) >= 32 ? lx : lx)];
      // note: +32 token-half shares the same XOR (bits 0-4 only)
      bf16x8 xf0 = frag_from_u4(ux0.x, ux0.y, ux0.z, ux0.w);
      bf16x8 xf1 = frag_from_u4(ux1.x, ux1.y, ux1.z, ux1.w);
      bf16x8 fw = *(const bf16x8*)(wqp + kt * 512 + lane * 8);
      a0 = MFMA32(fw, xf0, a0);  a1 = MFMA32(fw, xf1, a1);
    }
    #pragma unroll
    for (int kt = 0; kt < 2; ++kt) {
      fQ[0][kt] = makefrag(a0, kt, hf);
      fQ[1][kt] = makefrag(a1, kt, hf);
    }
  }

  // ---- pass K: K^T = Wk · X^T -------------------------------------------
  bf16x8 fK[2][2];
  {
    f32x16 a0 = zf, a1 = zf;
    #pragma unroll 4
    for (int kt = 0; kt < 16; ++kt) {
      int lx = l31 ^ (kt >> 1);
      int base = (2 * kt + hf) * 64;
      uint4 ux0 = ldsX[base + lx];
      uint4 ux1 = ldsX[base + 32 + lx];
      bf16x8 xf0 = frag_from_u4(ux0.x, ux0.y, ux0.z, ux0.w);
      bf16x8 xf1 = frag_from_u4(ux1.x, ux1.y, ux1.z, ux1.w);
      bf16x8 fw = *(const bf16x8*)(wkp + kt * 512 + lane * 8);
      a0 = MFMA32(fw, xf0, a0);  a1 = MFMA32(fw, xf1, a1);
    }
    #pragma unroll
    for (int kt = 0; kt < 2; ++kt) {
      fK[0][kt] = makefrag(a0, kt, hf);
      fK[1][kt] = makefrag(a1, kt, hf);
    }
  }

  // ---- bi-sequential S/softmax/P-conversion (AGPR peak 32) --------------
  const float* Bp = Bpack + ((((wy == 15) ? 2 : 0) | ((wx == 15) ? 1 : 0)) << 12);
  bf16x8 pf[2][4];
  float ri[2];
  #pragma unroll
  for (int bi = 0; bi < 2; ++bi) {
    f32x16 s0, s1;                         // S^T key-tiles ai=0,1 for this bi
    #pragma unroll
    for (int rb = 0; rb < 4; ++rb) {
      float4 f0 = *(const float4*)(Bp + ((bi * 4 + rb) * 64 + lane) * 4);
      float4 f1 = *(const float4*)(Bp + (((2 + bi) * 4 + rb) * 64 + lane) * 4);
      s0[rb * 4 + 0] = f0.x; s0[rb * 4 + 1] = f0.y;
      s0[rb * 4 + 2] = f0.z; s0[rb * 4 + 3] = f0.w;
      s1[rb * 4 + 0] = f1.x; s1[rb * 4 + 1] = f1.y;
      s1[rb * 4 + 2] = f1.z; s1[rb * 4 + 3] = f1.w;
    }
    #pragma unroll
    for (int kt = 0; kt < 2; ++kt) {
      s0 = MFMA32(fK[0][kt], fQ[bi][kt], s0);
      s1 = MFMA32(fK[1][kt], fQ[bi][kt], s1);
    }
    float mx = -3e38f;
    #pragma unroll
    for (int r = 0; r < 16; ++r) mx = fmaxf(mx, fmaxf(s0[r], s1[r]));
    mx = fmaxf(mx, __shfl_xor(mx, 32, 64));
    float sum = 0.0f;
    #pragma unroll
    for (int r = 0; r < 16; ++r) {
      float p0 = exp2f((s0[r] - mx) * LOG2E);
      float p1 = exp2f((s1[r] - mx) * LOG2E);
      s0[r] = p0; s1[r] = p1;
      sum += p0 + p1;
    }
    sum += __shfl_xor(sum, 32, 64);
    ri[bi] = 1.0f / sum;                   // deferred to ot scale
    #pragma unroll
    for (int kt = 0; kt < 2; ++kt) {
      pf[bi][kt]     = makefrag(s0, kt, hf);
      pf[bi][2 + kt] = makefrag(s1, kt, hf);
    }
  }

  // ---- pass V: V = X · Wv (fQ/fK dead) ----------------------------------
  bf16x8 fV[2][2];
  {
    f32x16 a0 = zf, a1 = zf;
    #pragma unroll 4
    for (int kt = 0; kt < 16; ++kt) {
      int lx = l31 ^ (kt >> 1);
      int base = (2 * kt + hf) * 64;
      uint4 ux0 = ldsX[base + lx];
      uint4 ux1 = ldsX[base + 32 + lx];
      bf16x8 xf0 = frag_from_u4(ux0.x, ux0.y, ux0.z, ux0.w);
      bf16x8 xf1 = frag_from_u4(ux1.x, ux1.y, ux1.z, ux1.w);
      bf16x8 fw = *(const bf16x8*)(wvp + kt * 512 + lane * 8);
      a0 = MFMA32(xf0, fw, a0);  a1 = MFMA32(xf1, fw, a1);
    }
    #pragma unroll
    for (int kt = 0; kt < 2; ++kt) {
      fV[0][kt] = makefrag(a0, kt, hf);
      fV[1][kt] = makefrag(a1, kt, hf);
    }
  }

  // ---- O^T = V^T · P^T  (ot[bi]: row=d, col=query token) ----------------
  f32x16 ot[2];
  ot[0] = zf; ot[1] = zf;
  #pragma unroll
  for (int jt = 0; jt < 4; ++jt) {
    bf16x8 aV = fV[jt >> 1][jt & 1];
    ot[0] = MFMA32(aV, pf[0][jt], ot[0]);
    ot[1] = MFMA32(aV, pf[1][jt], ot[1]);
  }
  #pragma unroll
  for (int bi = 0; bi < 2; ++bi)
    #pragma unroll
    for (int r = 0; r < 16; ++r) ot[bi][r] *= ri[bi];

  // all waves must be done reading ldsX before ldsO overwrites the union
  __syncthreads();

  // ---- O^T -> LDS bf16 (k = h*32 + d, k-grouped slots) ------------------
  {
    #pragma unroll
    for (int bi = 0; bi < 2; ++bi) {
      int tok = bi * 32 + l31;
      #pragma unroll
      for (int g = 0; g < 4; ++g) {
        int kg = h * 4 + g;                // d = 8g + 4hf + 0..3
        uint2 wv2;
        wv2.x = pack2(ot[bi][4 * g + 0], ot[bi][4 * g + 1]);
        wv2.y = pack2(ot[bi][4 * g + 2], ot[bi][4 * g + 3]);
        *(uint2*)&ldsO[(kg * 64 + tok) * 8 + 4 * hf] = wv2;
      }
    }
  }
  __syncthreads();

  // ---- out-proj: out^T = W_out^T · O^T  (wave h -> out cols h*32..+31) --
  const ushort* wop = WoPack + h * 8192;
  f32x16 u[2];
  u[0] = zf; u[1] = zf;
  #pragma unroll 4
  for (int kt = 0; kt < 16; ++kt) {
    int kg = 2 * kt + hf;
    bf16x8 wa = *(const bf16x8*)(wop + kt * 512 + lane * 8);
    bf16x8 b0 = *(const bf16x8*)&ldsO[(kg * 64 + l31) * 8];
    bf16x8 b1 = *(const bf16x8*)&ldsO[(kg * 64 + 32 + l31) * 8];
    u[0] = MFMA32(wa, b0, u[0]);
    u[1] = MFMA32(wa, b1, u[1]);
  }

  // ---- epilogue: + b_out, write fp32 with roll(+4,+4) folded in ---------
  #pragma unroll
  for (int tt = 0; tt < 2; ++tt) {
    int tok = 32 * tt + l31;
    int ty = tok >> 3, tx = tok & 7;
    int yy = (wy * 8 + ty + 4) & 127;
    int xx = (wx * 8 + tx + 4) & 127;
    float* ob = out + (((b * 128 + yy) * 128 + xx) << 8);
    #pragma unroll
    for (int g = 0; g < 4; ++g) {
      int c0 = h * 32 + 8 * g + 4 * hf;
      float4 bo = *(const float4*)(bout + c0);
      float4 v;
      v.x = (tt ? u[1][4 * g + 0] : u[0][4 * g + 0]) + bo.x;
      v.y = (tt ? u[1][4 * g + 1] : u[0][4 * g + 1]) + bo.y;
      v.z = (tt ? u[1][4 * g + 2] : u[0][4 * g + 2]) + bo.z;
      v.w = (tt ? u[1][4 * g + 3] : u[0][4 * g + 3]) + bo.w;
      *(float4*)(ob + c0) = v;
    }
  }
}

// ---------------------------------------------------------------------------
extern "C" void kernel_launch(void* const* d_in, const int* in_sizes, int n_in,
                              void* d_out, int out_size, void* d_ws, size_t ws_size,
                              hipStream_t stream) {
  const float* x    = (const float*)d_in[0];
  const float* wqkv = (const float*)d_in[1];
  const float* pos  = (const float*)d_in[2];
  const float* wout = (const float*)d_in[3];
  const float* bout = (const float*)d_in[4];

  ushort* Wpack  = (ushort*)d_ws;                     // [3][8][16][64][8] bf16
  ushort* WoPack = Wpack + 196608;                    // [8][16][64][8] bf16
  float*  Bpack  = (float*)((char*)d_ws + 524288);    // [4][2][2][4][64][4] f32

  prep_weights<<<1088, 256, 0, stream>>>(wqkv, wout, pos, Wpack, WoPack, Bpack);
  swin_attn<<<2048, 512, 0, stream>>>(x, bout, Wpack, WoPack, Bpack, (float*)d_out);
}